// Round 10
// baseline (757.919 us; speedup 1.0000x reference)
//
#include <hip/hip_runtime.h>
#include <math.h>

#define NBLEND 24
#define HDIM 128
#define KHALF 64
#define CHUNK 32                 // W1 rows staged per LDS chunk
#define NCHUNK (HDIM / CHUNK)
#define MAX_STEPS 10
#define CVG_T 1e-5f
#define DVG_T 1.0f
#define EPS_B 1e-6f

// 16 KB shared: W1 chunk buffer, time-aliased with the logit-exchange buffer
#define SMEM_BYTES (CHUNK * HDIM * 4)   // 16384 >= 12288 (part)

typedef float v2f __attribute__((ext_vector_type(2)));
typedef float v4f __attribute__((ext_vector_type(4)));

#if __has_builtin(__builtin_elementwise_fma)
#define VFMA(a, b, c) __builtin_elementwise_fma((a), (b), (c))
#define VFMA4(a, b, c) __builtin_elementwise_fma((a), (b), (c))
#else
static __device__ __forceinline__ v2f VFMA(v2f a, v2f b, v2f c) {
    v2f r; r.x = fmaf(a.x, b.x, c.x); r.y = fmaf(a.y, b.y, c.y); return r;
}
static __device__ __forceinline__ v4f VFMA4(v4f a, v4f b, v4f c) {
    v4f r;
    r.x = fmaf(a.x, b.x, c.x); r.y = fmaf(a.y, b.y, c.y);
    r.z = fmaf(a.z, b.z, c.z); r.w = fmaf(a.w, b.w, c.w);
    return r;
}
#endif

__device__ __forceinline__ float softplus_f(float x) {
    // jax.nn.softplus: max(x,0) + log1p(exp(-|x|)), numerically stable
    float e = __expf(-fabsf(x));
    return fmaxf(x, 0.0f) + __logf(1.0f + e);
}

// One g(x) evaluation, split across the block's wave PAIR (wave 0: k<64,
// wave 1: k>=64; 64 points, one per lane). W1 is staged through LDS in
// 32-row chunks (coalesced v4f copy) and consumed as ds_read broadcasts —
// this replaces the s_load W1 stream whose K$-miss latency was the R1-R9
// stall (per-eval time scaled with occupancy => latency-bound, m-R9).
// W0/W2/biases/tfs stay scalar (15 KB working set fits the scalar K$ once
// W1 vacates it). Partial logits are exchanged through the SAME 16 KB LDS
// region (time-aliased, barrier-disciplined). FMA chain per element is
// identical to R6/R9 => bit-identical results.
__device__ __forceinline__ void eval_g_pair(
    float* smem,                 // SMEM_BYTES, w1buf / part union (no restrict: aliased)
    int w, int lane, int tid,
    const float* __restrict__ W0, const float* __restrict__ b0,
    const float* __restrict__ W1, const float* __restrict__ b1,
    const float* __restrict__ W2, const float* __restrict__ b2,
    const float* __restrict__ tfs,
    float x0, float x1, float x2,
    float xd0, float xd1, float xd2,
    float& g0, float& g1, float& g2)
{
    float* w1buf = smem;
    v2f (*part)[NBLEND / 2][64] = (v2f (*)[NBLEND / 2][64])smem;

    v4f acc[KHALF / 4];
    {
        const v4f* __restrict__ b1v = (const v4f*)(b1 + w * KHALF);
        #pragma unroll
        for (int kk = 0; kk < KHALF / 4; ++kk) acc[kk] = b1v[kk];
    }
    v2f vx0 = {x0, x0}, vx1 = {x1, x1}, vx2 = {x2, x2};

    #pragma unroll 1
    for (int c = 0; c < NCHUNK; ++c) {
        // barrier: prior chunk (or prior eval's part reads) fully consumed
        __syncthreads();
        // stage chunk c: 16 KB, coalesced, 8 x (v4f load + ds_write_b128)/thread-pair
        {
            const v4f* __restrict__ g = (const v4f*)(W1 + c * CHUNK * HDIM);
            v4f* l = (v4f*)w1buf;
            #pragma unroll
            for (int i = 0; i < (CHUNK * HDIM / 4) / 128; ++i)
                l[i * 128 + tid] = g[i * 128 + tid];
        }
        __syncthreads();   // staged data visible to both waves

        // rank-1 accumulate over the chunk's 32 rows, W1 from LDS broadcast
        #pragma unroll 2
        for (int jj = 0; jj < CHUNK; jj += 2) {
            int j = c * CHUNK + jj;
            v2f z = *(const v2f*)(b0 + j);
            z = VFMA(vx0, *(const v2f*)(W0 + j), z);
            z = VFMA(vx1, *(const v2f*)(W0 + HDIM + j), z);
            z = VFMA(vx2, *(const v2f*)(W0 + 2 * HDIM + j), z);
            float ha = softplus_f(z.x);
            float hb = softplus_f(z.y);
            const v4f* r0 = (const v4f*)(w1buf + jj * HDIM + w * KHALF);
            const v4f* r1 = (const v4f*)(w1buf + (jj + 1) * HDIM + w * KHALF);
            v4f hva = {ha, ha, ha, ha}, hvb = {hb, hb, hb, hb};
            #pragma unroll
            for (int kk = 0; kk < KHALF / 4; ++kk) acc[kk] = VFMA4(hva, r0[kk], acc[kk]);
            #pragma unroll
            for (int kk = 0; kk < KHALF / 4; ++kk) acc[kk] = VFMA4(hvb, r1[kk], acc[kk]);
        }
    }
    #pragma unroll
    for (int kk = 0; kk < KHALF / 4; ++kk) {
        acc[kk].x = softplus_f(acc[kk].x);
        acc[kk].y = softplus_f(acc[kk].y);
        acc[kk].z = softplus_f(acc[kk].z);
        acc[kk].w = softplus_f(acc[kk].w);
    }

    // partial logits over own k-half (b2 added once, by wave 0); W2 scalar
    v2f lg[NBLEND / 2];
    if (w == 0) {
        const v2f* __restrict__ b2v = (const v2f*)b2;
        #pragma unroll
        for (int m2 = 0; m2 < NBLEND / 2; ++m2) lg[m2] = b2v[m2];
    } else {
        #pragma unroll
        for (int m2 = 0; m2 < NBLEND / 2; ++m2) lg[m2] = (v2f){0.f, 0.f};
    }
    const float* __restrict__ W2h = W2 + w * KHALF * NBLEND;
    #pragma unroll
    for (int kk = 0; kk < KHALF; ++kk) {
        float h1 = acc[kk >> 2][kk & 3];
        v2f hv = {h1, h1};
        const v2f* __restrict__ w2r = (const v2f*)(W2h + kk * NBLEND);
        #pragma unroll
        for (int m2 = 0; m2 < NBLEND / 2; ++m2) lg[m2] = VFMA(hv, w2r[m2], lg[m2]);
    }

    // exchange partials via LDS (aliased onto w1buf; all chunk reads done)
    __syncthreads();   // both waves finished reading w1buf
    #pragma unroll
    for (int m2 = 0; m2 < NBLEND / 2; ++m2) part[w][m2][lane] = lg[m2];
    __syncthreads();
    #pragma unroll
    for (int m2 = 0; m2 < NBLEND / 2; ++m2) lg[m2] += part[w ^ 1][m2][lane];
    // next shared access is the next eval's chunk-0 stage, behind its barrier

    // two-pass softmax over 24 logits (matches jax.nn.softmax)
    float M = -3.0e38f;
    #pragma unroll
    for (int m2 = 0; m2 < NBLEND / 2; ++m2)
        M = fmaxf(M, fmaxf(lg[m2].x, lg[m2].y));

    float S = 0.f;
    v2f T[6];
    #pragma unroll
    for (int t = 0; t < 6; ++t) T[t] = (v2f){0.f, 0.f};
    #pragma unroll
    for (int m = 0; m < NBLEND; ++m) {
        float lgm = (m & 1) ? lg[m >> 1].y : lg[m >> 1].x;
        float e = __expf(lgm - M);
        S += e;
        const v2f* __restrict__ tf = (const v2f*)(tfs + m * 12);
        v2f ev = {e, e};
        #pragma unroll
        for (int t = 0; t < 6; ++t) T[t] = VFMA(ev, tf[t], T[t]);
    }
    float inv = 1.0f / S;
    g0 = inv * fmaf(T[0].x, x0, fmaf(T[0].y, x1, fmaf(T[1].x, x2, T[1].y))) - xd0;
    g1 = inv * fmaf(T[2].x, x0, fmaf(T[2].y, x1, fmaf(T[3].x, x2, T[3].y))) - xd1;
    g2 = inv * fmaf(T[4].x, x0, fmaf(T[4].y, x1, fmaf(T[5].x, x2, T[5].y))) - xd2;
}

struct PState {
    float x0, x1, x2;
    float g0, g1, g2;
    float J[9];
    float u0, u1, u2;
    float xo0, xo1, xo2;
    float gno;
};

// One Broyden step (reference semantics, verified R1-R9).
__device__ __forceinline__ bool do_step_pair(
    float* smem, int w, int lane, int tid,
    const float* __restrict__ W0, const float* __restrict__ b0,
    const float* __restrict__ W1, const float* __restrict__ b1,
    const float* __restrict__ W2, const float* __restrict__ b2,
    const float* __restrict__ tfs,
    float xd0, float xd1, float xd2, PState& s)
{
    float dx0 = s.u0, dx1 = s.u1, dx2 = s.u2;
    s.x0 += dx0; s.x1 += dx1; s.x2 += dx2;

    float ng0, ng1, ng2;
    eval_g_pair(smem, w, lane, tid, W0, b0, W1, b1, W2, b2, tfs,
                s.x0, s.x1, s.x2, xd0, xd1, xd2, ng0, ng1, ng2);
    float dg0 = ng0 - s.g0, dg1 = ng1 - s.g1, dg2 = ng2 - s.g2;
    s.g0 = ng0; s.g1 = ng1; s.g2 = ng2;

    float gn = sqrtf(s.g0 * s.g0 + s.g1 * s.g1 + s.g2 * s.g2);
    bool better = gn < s.gno;                 // false for NaN (matches jnp.where)
    if (better) { s.gno = gn; s.xo0 = s.x0; s.xo1 = s.x1; s.xo2 = s.x2; }
    bool ids_new = (s.gno > CVG_T) && (gn < DVG_T);

    float vT0 = fmaf(dx0, s.J[0], fmaf(dx1, s.J[3], dx2 * s.J[6]));
    float vT1 = fmaf(dx0, s.J[1], fmaf(dx1, s.J[4], dx2 * s.J[7]));
    float vT2 = fmaf(dx0, s.J[2], fmaf(dx1, s.J[5], dx2 * s.J[8]));
    float a0 = dx0 - fmaf(s.J[0], dg0, fmaf(s.J[1], dg1, s.J[2] * dg2));
    float a1 = dx1 - fmaf(s.J[3], dg0, fmaf(s.J[4], dg1, s.J[5] * dg2));
    float a2 = dx2 - fmaf(s.J[6], dg0, fmaf(s.J[7], dg1, s.J[8] * dg2));
    float bb = fmaf(vT0, dg0, fmaf(vT1, dg1, vT2 * dg2));
    bb += (bb >= 0.f) ? EPS_B : -EPS_B;
    // select (NOT multiply) so NaN can't leak into J when masked off
    float iu0 = ids_new ? (a0 / bb) : 0.f;
    float iu1 = ids_new ? (a1 / bb) : 0.f;
    float iu2 = ids_new ? (a2 / bb) : 0.f;
    s.J[0] = fmaf(iu0, vT0, s.J[0]); s.J[1] = fmaf(iu0, vT1, s.J[1]); s.J[2] = fmaf(iu0, vT2, s.J[2]);
    s.J[3] = fmaf(iu1, vT0, s.J[3]); s.J[4] = fmaf(iu1, vT1, s.J[4]); s.J[5] = fmaf(iu1, vT2, s.J[5]);
    s.J[6] = fmaf(iu2, vT0, s.J[6]); s.J[7] = fmaf(iu2, vT1, s.J[7]); s.J[8] = fmaf(iu2, vT2, s.J[8]);

    s.u0 = -(fmaf(s.J[0], s.g0, fmaf(s.J[1], s.g1, s.J[2] * s.g2)));
    s.u1 = -(fmaf(s.J[3], s.g0, fmaf(s.J[4], s.g1, s.J[5] * s.g2)));
    s.u2 = -(fmaf(s.J[6], s.g0, fmaf(s.J[7], s.g1, s.J[8] * s.g2)));
    return ids_new;
}

// --- state SoA in d_ws: 22 arrays of N floats ---
// 0-2: x | 3-11: J | 12-14: g | 15-17: u | 18-20: xo | 21: gno

__device__ __forceinline__ void st_store(float* __restrict__ st, int N, int n,
                                         const PState& s) {
    st[0 * N + n] = s.x0; st[1 * N + n] = s.x1; st[2 * N + n] = s.x2;
    #pragma unroll
    for (int a = 0; a < 9; ++a) st[(3 + a) * N + n] = s.J[a];
    st[12 * N + n] = s.g0; st[13 * N + n] = s.g1; st[14 * N + n] = s.g2;
    st[15 * N + n] = s.u0; st[16 * N + n] = s.u1; st[17 * N + n] = s.u2;
    st[18 * N + n] = s.xo0; st[19 * N + n] = s.xo1; st[20 * N + n] = s.xo2;
    st[21 * N + n] = s.gno;
}

__device__ __forceinline__ void st_load(const float* __restrict__ st, int N, int n,
                                        PState& s) {
    s.x0 = st[0 * N + n]; s.x1 = st[1 * N + n]; s.x2 = st[2 * N + n];
    #pragma unroll
    for (int a = 0; a < 9; ++a) s.J[a] = st[(3 + a) * N + n];
    s.g0 = st[12 * N + n]; s.g1 = st[13 * N + n]; s.g2 = st[14 * N + n];
    s.u0 = st[15 * N + n]; s.u1 = st[16 * N + n]; s.u2 = st[17 * N + n];
    s.xo0 = st[18 * N + n]; s.xo1 = st[19 * N + n]; s.xo2 = st[20 * N + n];
    s.gno = st[21 * N + n];
}

__device__ __forceinline__ void write_out(float* __restrict__ out, int N, int n,
                                          const PState& s) {
    out[n * 3 + 0] = s.xo0;
    out[n * 3 + 1] = s.xo1;
    out[n * 3 + 2] = s.xo2;
    out[3 * N + n] = s.gno;
    out[4 * N + n] = (s.gno < CVG_T) ? 1.0f : 0.0f;
}

// init (eval0) fused with step 1 (reference: ids starts all-true)
__global__ void __launch_bounds__(128)
init_step1_kernel(const float* __restrict__ xd_p,
                  const float* __restrict__ x_init,
                  const float* __restrict__ Jinv_init,
                  const float* __restrict__ tfs,
                  const float* __restrict__ W0, const float* __restrict__ b0,
                  const float* __restrict__ W1, const float* __restrict__ b1,
                  const float* __restrict__ W2, const float* __restrict__ b2,
                  float* __restrict__ out, float* __restrict__ st,
                  int* __restrict__ qout, int* __restrict__ cnt_out, int N)
{
    __shared__ __align__(16) float smem[SMEM_BYTES / 4];
    const int tid = threadIdx.x;
    const int lane = tid & 63;
    const int w = __builtin_amdgcn_readfirstlane(tid >> 6);
    const int n = blockIdx.x * 64 + lane;   // N = 131072 = 2048*64 exact

    float xd0 = xd_p[n * 3 + 0], xd1 = xd_p[n * 3 + 1], xd2 = xd_p[n * 3 + 2];
    PState s;
    s.x0 = x_init[n * 3 + 0]; s.x1 = x_init[n * 3 + 1]; s.x2 = x_init[n * 3 + 2];
    #pragma unroll
    for (int a = 0; a < 9; ++a) s.J[a] = Jinv_init[n * 9 + a];

    eval_g_pair(smem, w, lane, tid, W0, b0, W1, b1, W2, b2, tfs,
                s.x0, s.x1, s.x2, xd0, xd1, xd2, s.g0, s.g1, s.g2);
    s.u0 = -(fmaf(s.J[0], s.g0, fmaf(s.J[1], s.g1, s.J[2] * s.g2)));
    s.u1 = -(fmaf(s.J[3], s.g0, fmaf(s.J[4], s.g1, s.J[5] * s.g2)));
    s.u2 = -(fmaf(s.J[6], s.g0, fmaf(s.J[7], s.g1, s.J[8] * s.g2)));
    s.gno = sqrtf(s.g0 * s.g0 + s.g1 * s.g1 + s.g2 * s.g2);
    s.xo0 = s.x0; s.xo1 = s.x1; s.xo2 = s.x2;

    bool alive = do_step_pair(smem, w, lane, tid, W0, b0, W1, b1, W2, b2, tfs,
                              xd0, xd1, xd2, s);
    if (w == 0) {
        if (alive) {
            int pos = atomicAdd(cnt_out, 1);
            qout[pos] = n;
            st_store(st, N, n, s);
        } else {
            write_out(out, N, n, s);
        }
    }
}

template<bool LAST>
__global__ void __launch_bounds__(128)
step_kernel(const float* __restrict__ xd_p,
            const float* __restrict__ tfs,
            const float* __restrict__ W0, const float* __restrict__ b0,
            const float* __restrict__ W1, const float* __restrict__ b1,
            const float* __restrict__ W2, const float* __restrict__ b2,
            float* __restrict__ out, float* __restrict__ st,
            const int* __restrict__ qin, const int* __restrict__ cnt_in,
            int* __restrict__ qout, int* __restrict__ cnt_out, int N)
{
    __shared__ __align__(16) float smem[SMEM_BYTES / 4];
    const int count = *cnt_in;                       // uniform -> s_load
    const int b = blockIdx.x;
    if (b * 64 >= count) return;                     // block-uniform exit (pre-barrier)
    const int tid = threadIdx.x;
    const int lane = tid & 63;
    const int w = __builtin_amdgcn_readfirstlane(tid >> 6);
    const int i = b * 64 + lane;
    const bool valid = i < count;
    const int qi = valid ? i : (count - 1);          // dummy lanes: barriers uniform
    const int n = qin[qi];

    float xd0 = xd_p[n * 3 + 0], xd1 = xd_p[n * 3 + 1], xd2 = xd_p[n * 3 + 2];
    PState s;
    st_load(st, N, n, s);

    bool alive = do_step_pair(smem, w, lane, tid, W0, b0, W1, b1, W2, b2, tfs,
                              xd0, xd1, xd2, s);
    if (w == 0 && valid) {
        if (!LAST && alive) {
            int pos = atomicAdd(cnt_out, 1);
            qout[pos] = n;
            st_store(st, N, n, s);
        } else {
            write_out(out, N, n, s);
        }
    }
}

// fallback: monolithic pair-split, used only if d_ws too small
__global__ void __launch_bounds__(128)
broyden_mono_kernel(const float* __restrict__ xd_p,
                    const float* __restrict__ x_init,
                    const float* __restrict__ Jinv_init,
                    const float* __restrict__ tfs,
                    const float* __restrict__ W0, const float* __restrict__ b0,
                    const float* __restrict__ W1, const float* __restrict__ b1,
                    const float* __restrict__ W2, const float* __restrict__ b2,
                    float* __restrict__ out, int N)
{
    __shared__ __align__(16) float smem[SMEM_BYTES / 4];
    const int tid = threadIdx.x;
    const int lane = tid & 63;
    const int w = __builtin_amdgcn_readfirstlane(tid >> 6);
    const int n = blockIdx.x * 64 + lane;

    float xd0 = xd_p[n * 3 + 0], xd1 = xd_p[n * 3 + 1], xd2 = xd_p[n * 3 + 2];
    PState s;
    s.x0 = x_init[n * 3 + 0]; s.x1 = x_init[n * 3 + 1]; s.x2 = x_init[n * 3 + 2];
    #pragma unroll
    for (int a = 0; a < 9; ++a) s.J[a] = Jinv_init[n * 9 + a];

    eval_g_pair(smem, w, lane, tid, W0, b0, W1, b1, W2, b2, tfs,
                s.x0, s.x1, s.x2, xd0, xd1, xd2, s.g0, s.g1, s.g2);
    s.u0 = -(fmaf(s.J[0], s.g0, fmaf(s.J[1], s.g1, s.J[2] * s.g2)));
    s.u1 = -(fmaf(s.J[3], s.g0, fmaf(s.J[4], s.g1, s.J[5] * s.g2)));
    s.u2 = -(fmaf(s.J[6], s.g0, fmaf(s.J[7], s.g1, s.J[8] * s.g2)));
    s.gno = sqrtf(s.g0 * s.g0 + s.g1 * s.g1 + s.g2 * s.g2);
    s.xo0 = s.x0; s.xo1 = s.x1; s.xo2 = s.x2;

    bool ids = true;
    for (int step = 0; step < MAX_STEPS; ++step) {
        if (__ballot(ids) == 0ull) break;
        float su0 = s.u0, su1 = s.u1, su2 = s.u2;
        if (!ids) { s.u0 = 0.f; s.u1 = 0.f; s.u2 = 0.f; }
        bool alive = do_step_pair(smem, w, lane, tid, W0, b0, W1, b1, W2, b2, tfs,
                                  xd0, xd1, xd2, s);
        ids = ids ? alive : false;
        (void)su0; (void)su1; (void)su2;
    }
    if (w == 0) write_out(out, N, n, s);
}

extern "C" void kernel_launch(void* const* d_in, const int* in_sizes, int n_in,
                              void* d_out, int out_size, void* d_ws, size_t ws_size,
                              hipStream_t stream) {
    const float* xd     = (const float*)d_in[0];
    const float* x_init = (const float*)d_in[1];
    const float* Jinv   = (const float*)d_in[2];
    const float* tfs    = (const float*)d_in[3];
    const float* W0     = (const float*)d_in[4];
    const float* b0     = (const float*)d_in[5];
    const float* W1     = (const float*)d_in[6];
    const float* b1     = (const float*)d_in[7];
    const float* W2     = (const float*)d_in[8];
    const float* b2     = (const float*)d_in[9];
    float* out = (float*)d_out;

    const int N = in_sizes[0] / 3;
    const int nb = (N + 63) / 64;      // blocks of 128 threads, 64 points each
    const size_t need = (size_t)24 * N * sizeof(float) + 64;

    if (ws_size >= need) {
        float* st = (float*)d_ws;
        int* q0 = (int*)((char*)d_ws + (size_t)22 * N * sizeof(float));
        int* q1 = q0 + N;
        int* cnt = q1 + N;                       // 16 ints
        hipMemsetAsync(cnt, 0, 16 * sizeof(int), stream);

        hipLaunchKernelGGL(init_step1_kernel, dim3(nb), dim3(128), 0, stream,
                           xd, x_init, Jinv, tfs, W0, b0, W1, b1, W2, b2,
                           out, st, q0, &cnt[0], N);

        int* qa = q0;
        int* qb = q1;
        for (int t = 2; t <= MAX_STEPS; ++t) {
            if (t < MAX_STEPS) {
                hipLaunchKernelGGL((step_kernel<false>), dim3(nb), dim3(128), 0, stream,
                                   xd, tfs, W0, b0, W1, b1, W2, b2, out, st,
                                   qa, &cnt[t - 2], qb, &cnt[t - 1], N);
            } else {
                hipLaunchKernelGGL((step_kernel<true>), dim3(nb), dim3(128), 0, stream,
                                   xd, tfs, W0, b0, W1, b1, W2, b2, out, st,
                                   qa, &cnt[t - 2], qb, &cnt[t - 1], N);
            }
            int* tmp = qa; qa = qb; qb = tmp;
        }
    } else {
        hipLaunchKernelGGL(broyden_mono_kernel, dim3(nb), dim3(128), 0, stream,
                           xd, x_init, Jinv, tfs, W0, b0, W1, b1, W2, b2, out, N);
    }
}

// Round 11
// 476.921 us; speedup vs baseline: 1.5892x; 1.5892x over previous
//
#include <hip/hip_runtime.h>
#include <math.h>

#define NBLEND 24
#define HDIM 128
#define KHALF 64
#define MAX_STEPS 10
#define CVG_T 1e-5f
#define DVG_T 1.0f
#define EPS_B 1e-6f

typedef float v2f __attribute__((ext_vector_type(2)));

#if __has_builtin(__builtin_elementwise_fma)
#define VFMA(a, b, c) __builtin_elementwise_fma((a), (b), (c))
#else
static __device__ __forceinline__ v2f VFMA(v2f a, v2f b, v2f c) {
    v2f r; r.x = fmaf(a.x, b.x, c.x); r.y = fmaf(a.y, b.y, c.y); return r;
}
#endif

__device__ __forceinline__ float softplus_f(float x) {
    // jax.nn.softplus: max(x,0) + log1p(exp(-|x|)), numerically stable
    float e = __expf(-fabsf(x));
    return fmaxf(x, 0.0f) + __logf(1.0f + e);
}

// One g(x) evaluation, split across the block's wave PAIR (R6 body, 36 us
// per full-N eval proven): wave 0 handles k in [0,64), wave 1 k in [64,128),
// same 64 points (one per lane). Weights via wave-uniform s_load (SGPR
// operand broadcast is free in the VALU operand network — LDS/VMEM broadcast
// both measured slower, R7/R10). Partial logits combined via LDS; both waves
// hold identical full logits and compute identical g (f32 add commutative).
// CODE-SIZE DISCIPLINE: exactly ONE inlined copy of this function per kernel
// (R6-vs-R9 evidence: a second hot unrolled copy costs ~3.5x per eval — I$).
__device__ __forceinline__ void eval_g_pair(
    v2f (&part)[2][NBLEND / 2][64],
    int w, int lane,
    const float* __restrict__ W0, const float* __restrict__ b0,
    const float* __restrict__ W1, const float* __restrict__ b1,
    const float* __restrict__ W2, const float* __restrict__ b2,
    const float* __restrict__ tfs,
    float x0, float x1, float x2,
    float xd0, float xd1, float xd2,
    float& g0, float& g1, float& g2)
{
    v2f acc[KHALF / 2];
    {
        const v2f* __restrict__ b1v = (const v2f*)(b1 + w * KHALF);
        #pragma unroll
        for (int kk = 0; kk < KHALF / 2; ++kk) acc[kk] = b1v[kk];
    }
    const float* __restrict__ W1h = W1 + w * KHALF;
    v2f vx0 = {x0, x0}, vx1 = {x1, x1}, vx2 = {x2, x2};

    #pragma unroll 2
    for (int j = 0; j < HDIM; j += 2) {
        v2f z = *(const v2f*)(b0 + j);
        z = VFMA(vx0, *(const v2f*)(W0 + j), z);
        z = VFMA(vx1, *(const v2f*)(W0 + HDIM + j), z);
        z = VFMA(vx2, *(const v2f*)(W0 + 2 * HDIM + j), z);
        float ha = softplus_f(z.x);
        float hb = softplus_f(z.y);
        const v2f* __restrict__ r0 = (const v2f*)(W1h + j * HDIM);
        const v2f* __restrict__ r1 = (const v2f*)(W1h + (j + 1) * HDIM);
        v2f hva = {ha, ha}, hvb = {hb, hb};
        #pragma unroll
        for (int kk = 0; kk < KHALF / 2; ++kk) acc[kk] = VFMA(hva, r0[kk], acc[kk]);
        #pragma unroll
        for (int kk = 0; kk < KHALF / 2; ++kk) acc[kk] = VFMA(hvb, r1[kk], acc[kk]);
    }
    #pragma unroll
    for (int kk = 0; kk < KHALF / 2; ++kk) {
        acc[kk].x = softplus_f(acc[kk].x);
        acc[kk].y = softplus_f(acc[kk].y);
    }

    // partial logits over own k-half (b2 added once, by wave 0).
    // NOTE: loops fully unrolled so acc/lg indexing stays compile-time (no scratch).
    v2f lg[NBLEND / 2];
    if (w == 0) {
        const v2f* __restrict__ b2v = (const v2f*)b2;
        #pragma unroll
        for (int m2 = 0; m2 < NBLEND / 2; ++m2) lg[m2] = b2v[m2];
    } else {
        #pragma unroll
        for (int m2 = 0; m2 < NBLEND / 2; ++m2) lg[m2] = (v2f){0.f, 0.f};
    }
    const float* __restrict__ W2h = W2 + w * KHALF * NBLEND;
    #pragma unroll
    for (int kk = 0; kk < KHALF; ++kk) {
        float h1 = (kk & 1) ? acc[kk >> 1].y : acc[kk >> 1].x;
        v2f hv = {h1, h1};
        const v2f* __restrict__ w2r = (const v2f*)(W2h + kk * NBLEND);
        #pragma unroll
        for (int m2 = 0; m2 < NBLEND / 2; ++m2) lg[m2] = VFMA(hv, w2r[m2], lg[m2]);
    }

    // exchange partials with the partner wave
    #pragma unroll
    for (int m2 = 0; m2 < NBLEND / 2; ++m2) part[w][m2][lane] = lg[m2];
    __syncthreads();
    #pragma unroll
    for (int m2 = 0; m2 < NBLEND / 2; ++m2) lg[m2] += part[w ^ 1][m2][lane];
    __syncthreads();   // WAR: safe to overwrite part[] on the next eval

    // two-pass softmax over 24 logits (matches jax.nn.softmax)
    float M = -3.0e38f;
    #pragma unroll
    for (int m2 = 0; m2 < NBLEND / 2; ++m2)
        M = fmaxf(M, fmaxf(lg[m2].x, lg[m2].y));

    float S = 0.f;
    v2f T[6];
    #pragma unroll
    for (int t = 0; t < 6; ++t) T[t] = (v2f){0.f, 0.f};
    #pragma unroll
    for (int m = 0; m < NBLEND; ++m) {
        float lgm = (m & 1) ? lg[m >> 1].y : lg[m >> 1].x;
        float e = __expf(lgm - M);
        S += e;
        const v2f* __restrict__ tf = (const v2f*)(tfs + m * 12);
        v2f ev = {e, e};
        #pragma unroll
        for (int t = 0; t < 6; ++t) T[t] = VFMA(ev, tf[t], T[t]);
    }
    float inv = 1.0f / S;
    g0 = inv * fmaf(T[0].x, x0, fmaf(T[0].y, x1, fmaf(T[1].x, x2, T[1].y))) - xd0;
    g1 = inv * fmaf(T[2].x, x0, fmaf(T[2].y, x1, fmaf(T[3].x, x2, T[3].y))) - xd1;
    g2 = inv * fmaf(T[4].x, x0, fmaf(T[4].y, x1, fmaf(T[5].x, x2, T[5].y))) - xd2;
}

struct PState {
    float x0, x1, x2;
    float g0, g1, g2;
    float J[9];
    float u0, u1, u2;
    float xo0, xo1, xo2;
    float gno;
};

// Unified iteration: first=true -> initial eval (sets g,u,gn_opt,x_opt,
// returns true, matching reference ids=ones init). first=false -> one
// Broyden step with per-lane freeze via dx=0 (algebraically exact: dx=0 =>
// dg=0 => a=0 => iu=0 => J,u,gn,xo all fixed points; NaN guarded by selects).
// Contains the kernel's ONE eval call site.
__device__ __forceinline__ bool do_unified(
    bool first, bool alive,
    v2f (&part)[2][NBLEND / 2][64], int w, int lane,
    const float* __restrict__ W0, const float* __restrict__ b0,
    const float* __restrict__ W1, const float* __restrict__ b1,
    const float* __restrict__ W2, const float* __restrict__ b2,
    const float* __restrict__ tfs,
    float xd0, float xd1, float xd2, PState& s)
{
    float dx0 = (!first && alive) ? s.u0 : 0.f;
    float dx1 = (!first && alive) ? s.u1 : 0.f;
    float dx2 = (!first && alive) ? s.u2 : 0.f;
    s.x0 += dx0; s.x1 += dx1; s.x2 += dx2;

    float ng0, ng1, ng2;
    eval_g_pair(part, w, lane, W0, b0, W1, b1, W2, b2, tfs,
                s.x0, s.x1, s.x2, xd0, xd1, xd2, ng0, ng1, ng2);

    if (first) {
        s.g0 = ng0; s.g1 = ng1; s.g2 = ng2;
        s.gno = sqrtf(ng0 * ng0 + ng1 * ng1 + ng2 * ng2);
        s.xo0 = s.x0; s.xo1 = s.x1; s.xo2 = s.x2;
        s.u0 = -(fmaf(s.J[0], ng0, fmaf(s.J[1], ng1, s.J[2] * ng2)));
        s.u1 = -(fmaf(s.J[3], ng0, fmaf(s.J[4], ng1, s.J[5] * ng2)));
        s.u2 = -(fmaf(s.J[6], ng0, fmaf(s.J[7], ng1, s.J[8] * ng2)));
        return true;   // reference: ids = ones before the scan
    }

    float dg0 = ng0 - s.g0, dg1 = ng1 - s.g1, dg2 = ng2 - s.g2;
    s.g0 = ng0; s.g1 = ng1; s.g2 = ng2;

    float gn = sqrtf(s.g0 * s.g0 + s.g1 * s.g1 + s.g2 * s.g2);
    bool better = gn < s.gno;                 // false for NaN (matches jnp.where)
    if (better) { s.gno = gn; s.xo0 = s.x0; s.xo1 = s.x1; s.xo2 = s.x2; }
    bool ids_new = (s.gno > CVG_T) && (gn < DVG_T);

    float vT0 = fmaf(dx0, s.J[0], fmaf(dx1, s.J[3], dx2 * s.J[6]));
    float vT1 = fmaf(dx0, s.J[1], fmaf(dx1, s.J[4], dx2 * s.J[7]));
    float vT2 = fmaf(dx0, s.J[2], fmaf(dx1, s.J[5], dx2 * s.J[8]));
    float a0 = dx0 - fmaf(s.J[0], dg0, fmaf(s.J[1], dg1, s.J[2] * dg2));
    float a1 = dx1 - fmaf(s.J[3], dg0, fmaf(s.J[4], dg1, s.J[5] * dg2));
    float a2 = dx2 - fmaf(s.J[6], dg0, fmaf(s.J[7], dg1, s.J[8] * dg2));
    float bb = fmaf(vT0, dg0, fmaf(vT1, dg1, vT2 * dg2));
    bb += (bb >= 0.f) ? EPS_B : -EPS_B;
    // select (NOT multiply) so NaN can't leak into J when masked off
    float iu0 = ids_new ? (a0 / bb) : 0.f;
    float iu1 = ids_new ? (a1 / bb) : 0.f;
    float iu2 = ids_new ? (a2 / bb) : 0.f;
    s.J[0] = fmaf(iu0, vT0, s.J[0]); s.J[1] = fmaf(iu0, vT1, s.J[1]); s.J[2] = fmaf(iu0, vT2, s.J[2]);
    s.J[3] = fmaf(iu1, vT0, s.J[3]); s.J[4] = fmaf(iu1, vT1, s.J[4]); s.J[5] = fmaf(iu1, vT2, s.J[5]);
    s.J[6] = fmaf(iu2, vT0, s.J[6]); s.J[7] = fmaf(iu2, vT1, s.J[7]); s.J[8] = fmaf(iu2, vT2, s.J[8]);

    s.u0 = -(fmaf(s.J[0], s.g0, fmaf(s.J[1], s.g1, s.J[2] * s.g2)));
    s.u1 = -(fmaf(s.J[3], s.g0, fmaf(s.J[4], s.g1, s.J[5] * s.g2)));
    s.u2 = -(fmaf(s.J[6], s.g0, fmaf(s.J[7], s.g1, s.J[8] * s.g2)));
    return ids_new;
}

// --- state SoA in d_ws: 22 arrays of N floats ---
// 0-2: x | 3-11: J | 12-14: g | 15-17: u | 18-20: xo | 21: gno

__device__ __forceinline__ void st_store(float* __restrict__ st, int N, int n,
                                         const PState& s) {
    st[0 * N + n] = s.x0; st[1 * N + n] = s.x1; st[2 * N + n] = s.x2;
    #pragma unroll
    for (int a = 0; a < 9; ++a) st[(3 + a) * N + n] = s.J[a];
    st[12 * N + n] = s.g0; st[13 * N + n] = s.g1; st[14 * N + n] = s.g2;
    st[15 * N + n] = s.u0; st[16 * N + n] = s.u1; st[17 * N + n] = s.u2;
    st[18 * N + n] = s.xo0; st[19 * N + n] = s.xo1; st[20 * N + n] = s.xo2;
    st[21 * N + n] = s.gno;
}

__device__ __forceinline__ void st_load(const float* __restrict__ st, int N, int n,
                                        PState& s) {
    s.x0 = st[0 * N + n]; s.x1 = st[1 * N + n]; s.x2 = st[2 * N + n];
    #pragma unroll
    for (int a = 0; a < 9; ++a) s.J[a] = st[(3 + a) * N + n];
    s.g0 = st[12 * N + n]; s.g1 = st[13 * N + n]; s.g2 = st[14 * N + n];
    s.u0 = st[15 * N + n]; s.u1 = st[16 * N + n]; s.u2 = st[17 * N + n];
    s.xo0 = st[18 * N + n]; s.xo1 = st[19 * N + n]; s.xo2 = st[20 * N + n];
    s.gno = st[21 * N + n];
}

__device__ __forceinline__ void write_out(float* __restrict__ out, int N, int n,
                                          const PState& s) {
    out[n * 3 + 0] = s.xo0;
    out[n * 3 + 1] = s.xo1;
    out[n * 3 + 2] = s.xo2;
    out[3 * N + n] = s.gno;
    out[4 * N + n] = (s.gno < CVG_T) ? 1.0f : 0.0f;
}

// eval0 + step1, as a ROLLED 2-iteration loop -> ONE eval copy in this kernel
__global__ void __launch_bounds__(128)
init_step1_kernel(const float* __restrict__ xd_p,
                  const float* __restrict__ x_init,
                  const float* __restrict__ Jinv_init,
                  const float* __restrict__ tfs,
                  const float* __restrict__ W0, const float* __restrict__ b0,
                  const float* __restrict__ W1, const float* __restrict__ b1,
                  const float* __restrict__ W2, const float* __restrict__ b2,
                  float* __restrict__ out, float* __restrict__ st,
                  int* __restrict__ qout, int* __restrict__ cnt_out, int N)
{
    __shared__ v2f part[2][NBLEND / 2][64];
    const int tid = threadIdx.x;
    const int lane = tid & 63;
    const int w = __builtin_amdgcn_readfirstlane(tid >> 6);
    const int n = blockIdx.x * 64 + lane;   // N = 131072 = 2048*64 exact

    float xd0 = xd_p[n * 3 + 0], xd1 = xd_p[n * 3 + 1], xd2 = xd_p[n * 3 + 2];
    PState s;
    s.x0 = x_init[n * 3 + 0]; s.x1 = x_init[n * 3 + 1]; s.x2 = x_init[n * 3 + 2];
    #pragma unroll
    for (int a = 0; a < 9; ++a) s.J[a] = Jinv_init[n * 9 + a];

    bool alive = true;
    #pragma unroll 1
    for (int it = 0; it < 2; ++it) {
        bool r = do_unified(it == 0, alive, part, w, lane,
                            W0, b0, W1, b1, W2, b2, tfs, xd0, xd1, xd2, s);
        alive = alive && r;
    }

    if (w == 0) {
        if (alive) {
            int pos = atomicAdd(cnt_out, 1);
            qout[pos] = n;
            st_store(st, N, n, s);
        } else {
            write_out(out, N, n, s);
        }
    }
}

// one compacted step (steps 2 and 3)
__global__ void __launch_bounds__(128)
step_kernel(const float* __restrict__ xd_p,
            const float* __restrict__ tfs,
            const float* __restrict__ W0, const float* __restrict__ b0,
            const float* __restrict__ W1, const float* __restrict__ b1,
            const float* __restrict__ W2, const float* __restrict__ b2,
            float* __restrict__ out, float* __restrict__ st,
            const int* __restrict__ qin, const int* __restrict__ cnt_in,
            int* __restrict__ qout, int* __restrict__ cnt_out, int N)
{
    __shared__ v2f part[2][NBLEND / 2][64];
    const int count = *cnt_in;                       // uniform -> s_load
    const int b = blockIdx.x;
    if (b * 64 >= count) return;                     // block-uniform exit
    const int tid = threadIdx.x;
    const int lane = tid & 63;
    const int w = __builtin_amdgcn_readfirstlane(tid >> 6);
    const int i = b * 64 + lane;
    const bool valid = i < count;
    const int qi = valid ? i : (count - 1);          // dummy lanes: barriers uniform
    const int n = qin[qi];

    float xd0 = xd_p[n * 3 + 0], xd1 = xd_p[n * 3 + 1], xd2 = xd_p[n * 3 + 2];
    PState s;
    st_load(st, N, n, s);

    bool alive = do_unified(false, true, part, w, lane,
                            W0, b0, W1, b1, W2, b2, tfs, xd0, xd1, xd2, s);
    if (w == 0 && valid) {
        if (alive) {
            int pos = atomicAdd(cnt_out, 1);
            qout[pos] = n;
            st_store(st, N, n, s);
        } else {
            write_out(out, N, n, s);
        }
    }
}

// merged tail: steps 4..MAX_STEPS in one kernel, internal loop + ballot exit
__global__ void __launch_bounds__(128)
tail_kernel(const float* __restrict__ xd_p,
            const float* __restrict__ tfs,
            const float* __restrict__ W0, const float* __restrict__ b0,
            const float* __restrict__ W1, const float* __restrict__ b1,
            const float* __restrict__ W2, const float* __restrict__ b2,
            float* __restrict__ out, float* __restrict__ st,
            const int* __restrict__ qin, const int* __restrict__ cnt_in, int N)
{
    __shared__ v2f part[2][NBLEND / 2][64];
    const int count = *cnt_in;
    const int b = blockIdx.x;
    if (b * 64 >= count) return;
    const int tid = threadIdx.x;
    const int lane = tid & 63;
    const int w = __builtin_amdgcn_readfirstlane(tid >> 6);
    const int i = b * 64 + lane;
    const bool valid = i < count;
    const int qi = valid ? i : (count - 1);
    const int n = qin[qi];

    float xd0 = xd_p[n * 3 + 0], xd1 = xd_p[n * 3 + 1], xd2 = xd_p[n * 3 + 2];
    PState s;
    st_load(st, N, n, s);

    bool alive = true;   // queued points are alive by construction
    #pragma unroll 1
    for (int it = 0; it < MAX_STEPS - 3; ++it) {
        // both waves hold identical per-lane alive -> identical ballot ->
        // the break is pair-uniform; eval barriers stay aligned
        if (__ballot(alive) == 0ull) break;
        bool r = do_unified(false, alive, part, w, lane,
                            W0, b0, W1, b1, W2, b2, tfs, xd0, xd1, xd2, s);
        alive = alive && r;
    }
    if (w == 0 && valid) write_out(out, N, n, s);
}

// fallback: monolithic pair-split (single eval copy), if d_ws too small
__global__ void __launch_bounds__(128)
broyden_mono_kernel(const float* __restrict__ xd_p,
                    const float* __restrict__ x_init,
                    const float* __restrict__ Jinv_init,
                    const float* __restrict__ tfs,
                    const float* __restrict__ W0, const float* __restrict__ b0,
                    const float* __restrict__ W1, const float* __restrict__ b1,
                    const float* __restrict__ W2, const float* __restrict__ b2,
                    float* __restrict__ out, int N)
{
    __shared__ v2f part[2][NBLEND / 2][64];
    const int tid = threadIdx.x;
    const int lane = tid & 63;
    const int w = __builtin_amdgcn_readfirstlane(tid >> 6);
    const int n = blockIdx.x * 64 + lane;

    float xd0 = xd_p[n * 3 + 0], xd1 = xd_p[n * 3 + 1], xd2 = xd_p[n * 3 + 2];
    PState s;
    s.x0 = x_init[n * 3 + 0]; s.x1 = x_init[n * 3 + 1]; s.x2 = x_init[n * 3 + 2];
    #pragma unroll
    for (int a = 0; a < 9; ++a) s.J[a] = Jinv_init[n * 9 + a];

    bool alive = true;
    #pragma unroll 1
    for (int it = 0; it <= MAX_STEPS; ++it) {
        if (it > 0 && __ballot(alive) == 0ull) break;
        bool r = do_unified(it == 0, alive, part, w, lane,
                            W0, b0, W1, b1, W2, b2, tfs, xd0, xd1, xd2, s);
        alive = (it == 0) ? true : (alive && r);
    }
    if (w == 0) write_out(out, N, n, s);
}

extern "C" void kernel_launch(void* const* d_in, const int* in_sizes, int n_in,
                              void* d_out, int out_size, void* d_ws, size_t ws_size,
                              hipStream_t stream) {
    const float* xd     = (const float*)d_in[0];
    const float* x_init = (const float*)d_in[1];
    const float* Jinv   = (const float*)d_in[2];
    const float* tfs    = (const float*)d_in[3];
    const float* W0     = (const float*)d_in[4];
    const float* b0     = (const float*)d_in[5];
    const float* W1     = (const float*)d_in[6];
    const float* b1     = (const float*)d_in[7];
    const float* W2     = (const float*)d_in[8];
    const float* b2     = (const float*)d_in[9];
    float* out = (float*)d_out;

    const int N = in_sizes[0] / 3;
    const int nb = (N + 63) / 64;      // blocks of 128 threads, 64 points each
    const size_t need = (size_t)24 * N * sizeof(float) + 64;

    if (ws_size >= need) {
        float* st = (float*)d_ws;
        int* q0 = (int*)((char*)d_ws + (size_t)22 * N * sizeof(float));
        int* q1 = q0 + N;
        int* cnt = q1 + N;                       // 16 ints
        hipMemsetAsync(cnt, 0, 16 * sizeof(int), stream);

        // eval0 + step1 (compact) -> step2 (compact) -> step3 (compact) -> steps 4..10 merged
        hipLaunchKernelGGL(init_step1_kernel, dim3(nb), dim3(128), 0, stream,
                           xd, x_init, Jinv, tfs, W0, b0, W1, b1, W2, b2,
                           out, st, q0, &cnt[0], N);
        hipLaunchKernelGGL(step_kernel, dim3(nb), dim3(128), 0, stream,
                           xd, tfs, W0, b0, W1, b1, W2, b2, out, st,
                           q0, &cnt[0], q1, &cnt[1], N);
        hipLaunchKernelGGL(step_kernel, dim3(nb), dim3(128), 0, stream,
                           xd, tfs, W0, b0, W1, b1, W2, b2, out, st,
                           q1, &cnt[1], q0, &cnt[2], N);
        hipLaunchKernelGGL(tail_kernel, dim3(nb), dim3(128), 0, stream,
                           xd, tfs, W0, b0, W1, b1, W2, b2, out, st,
                           q0, &cnt[2], N);
    } else {
        hipLaunchKernelGGL(broyden_mono_kernel, dim3(nb), dim3(128), 0, stream,
                           xd, x_init, Jinv, tfs, W0, b0, W1, b1, W2, b2, out, N);
    }
}

// Round 12
// 374.127 us; speedup vs baseline: 2.0258x; 1.2748x over previous
//
#include <hip/hip_runtime.h>
#include <math.h>

#define NBLEND 24
#define HDIM 128
#define KQ 32                    // k-columns per wave (4-way split)
#define MAX_STEPS 10
#define CVG_T 1e-5f
#define DVG_T 1.0f
#define EPS_B 1e-6f

typedef float v2f __attribute__((ext_vector_type(2)));

#if __has_builtin(__builtin_elementwise_fma)
#define VFMA(a, b, c) __builtin_elementwise_fma((a), (b), (c))
#else
static __device__ __forceinline__ v2f VFMA(v2f a, v2f b, v2f c) {
    v2f r; r.x = fmaf(a.x, b.x, c.x); r.y = fmaf(a.y, b.y, c.y); return r;
}
#endif

__device__ __forceinline__ float softplus_f(float x) {
    // jax.nn.softplus: max(x,0) + log1p(exp(-|x|)), numerically stable
    float e = __expf(-fabsf(x));
    return fmaxf(x, 0.0f) + __logf(1.0f + e);
}

// One g(x) evaluation, split across the block's FOUR waves: wave w handles
// k in [w*32, w*32+32) of the hidden dim for the same 64 points (one per
// lane). Halves each wave's per-eval s_load stream vs the 2-way split
// (16 KB vs 32 KB) — per-wave latency exposure drops below per-SIMD pipe
// demand at 4 waves/block. Weights stay on the wave-uniform scalar path
// (SGPR operand broadcast is free; VMEM/LDS broadcast measured slower,
// R7/R10). Partial logits all-to-all through LDS in FIXED order
// (b2+p0+p1+p2+p3) so all four waves compute bit-identical g.
__device__ __forceinline__ void eval_g_quad(
    v2f (&part)[4][NBLEND / 2][64],
    int w, int lane,
    const float* __restrict__ W0, const float* __restrict__ b0,
    const float* __restrict__ W1, const float* __restrict__ b1,
    const float* __restrict__ W2, const float* __restrict__ b2,
    const float* __restrict__ tfs,
    float x0, float x1, float x2,
    float xd0, float xd1, float xd2,
    float& g0, float& g1, float& g2)
{
    v2f acc[KQ / 2];
    {
        const v2f* __restrict__ b1v = (const v2f*)(b1 + w * KQ);
        #pragma unroll
        for (int kk = 0; kk < KQ / 2; ++kk) acc[kk] = b1v[kk];
    }
    const float* __restrict__ W1h = W1 + w * KQ;
    v2f vx0 = {x0, x0}, vx1 = {x1, x1}, vx2 = {x2, x2};

    #pragma unroll 2
    for (int j = 0; j < HDIM; j += 2) {
        v2f z = *(const v2f*)(b0 + j);
        z = VFMA(vx0, *(const v2f*)(W0 + j), z);
        z = VFMA(vx1, *(const v2f*)(W0 + HDIM + j), z);
        z = VFMA(vx2, *(const v2f*)(W0 + 2 * HDIM + j), z);
        float ha = softplus_f(z.x);
        float hb = softplus_f(z.y);
        const v2f* __restrict__ r0 = (const v2f*)(W1h + j * HDIM);
        const v2f* __restrict__ r1 = (const v2f*)(W1h + (j + 1) * HDIM);
        v2f hva = {ha, ha}, hvb = {hb, hb};
        #pragma unroll
        for (int kk = 0; kk < KQ / 2; ++kk) acc[kk] = VFMA(hva, r0[kk], acc[kk]);
        #pragma unroll
        for (int kk = 0; kk < KQ / 2; ++kk) acc[kk] = VFMA(hvb, r1[kk], acc[kk]);
    }
    #pragma unroll
    for (int kk = 0; kk < KQ / 2; ++kk) {
        acc[kk].x = softplus_f(acc[kk].x);
        acc[kk].y = softplus_f(acc[kk].y);
    }

    // raw partial logits over own k-slice (no b2 here; added in fixed order below)
    v2f lgp[NBLEND / 2];
    #pragma unroll
    for (int m2 = 0; m2 < NBLEND / 2; ++m2) lgp[m2] = (v2f){0.f, 0.f};
    const float* __restrict__ W2h = W2 + w * KQ * NBLEND;
    #pragma unroll
    for (int kk = 0; kk < KQ; ++kk) {
        float h1 = (kk & 1) ? acc[kk >> 1].y : acc[kk >> 1].x;
        v2f hv = {h1, h1};
        const v2f* __restrict__ w2r = (const v2f*)(W2h + kk * NBLEND);
        #pragma unroll
        for (int m2 = 0; m2 < NBLEND / 2; ++m2) lgp[m2] = VFMA(hv, w2r[m2], lgp[m2]);
    }

    // all-to-all exchange; every wave sums in the SAME order -> identical g
    #pragma unroll
    for (int m2 = 0; m2 < NBLEND / 2; ++m2) part[w][m2][lane] = lgp[m2];
    __syncthreads();
    v2f lg[NBLEND / 2];
    {
        const v2f* __restrict__ b2v = (const v2f*)b2;
        #pragma unroll
        for (int m2 = 0; m2 < NBLEND / 2; ++m2)
            lg[m2] = ((b2v[m2] + part[0][m2][lane]) + part[1][m2][lane])
                     + (part[2][m2][lane] + part[3][m2][lane]);
    }
    __syncthreads();   // WAR: safe to overwrite part[] on the next eval

    // two-pass softmax over 24 logits (matches jax.nn.softmax)
    float M = -3.0e38f;
    #pragma unroll
    for (int m2 = 0; m2 < NBLEND / 2; ++m2)
        M = fmaxf(M, fmaxf(lg[m2].x, lg[m2].y));

    float S = 0.f;
    v2f T[6];
    #pragma unroll
    for (int t = 0; t < 6; ++t) T[t] = (v2f){0.f, 0.f};
    #pragma unroll
    for (int m = 0; m < NBLEND; ++m) {
        float lgm = (m & 1) ? lg[m >> 1].y : lg[m >> 1].x;
        float e = __expf(lgm - M);
        S += e;
        const v2f* __restrict__ tf = (const v2f*)(tfs + m * 12);
        v2f ev = {e, e};
        #pragma unroll
        for (int t = 0; t < 6; ++t) T[t] = VFMA(ev, tf[t], T[t]);
    }
    float inv = 1.0f / S;
    g0 = inv * fmaf(T[0].x, x0, fmaf(T[0].y, x1, fmaf(T[1].x, x2, T[1].y))) - xd0;
    g1 = inv * fmaf(T[2].x, x0, fmaf(T[2].y, x1, fmaf(T[3].x, x2, T[3].y))) - xd1;
    g2 = inv * fmaf(T[4].x, x0, fmaf(T[4].y, x1, fmaf(T[5].x, x2, T[5].y))) - xd2;
}

// Monolithic Broyden solver: 1 block = 4 waves = 64 points. All four waves
// carry bit-identical per-point state -> identical per-lane ids -> identical
// ballot -> the early break is block-uniform and eval barriers stay aligned.
// R6 step structure (explicit init + loop; R11 proved rolled/predicated is
// slower). Frozen lanes take dx=0, which is an exact fixed point of the
// update (dg=0 -> a=0 -> iu=0 -> J,u,gn,xo unchanged; NaN guarded by selects).
__global__ void __launch_bounds__(256)
broyden_quad_kernel(const float* __restrict__ xd_p,
                    const float* __restrict__ x_init,
                    const float* __restrict__ Jinv_init,
                    const float* __restrict__ tfs,
                    const float* __restrict__ W0, const float* __restrict__ b0,
                    const float* __restrict__ W1, const float* __restrict__ b1,
                    const float* __restrict__ W2, const float* __restrict__ b2,
                    float* __restrict__ out, int N)
{
    __shared__ v2f part[4][NBLEND / 2][64];
    const int tid = threadIdx.x;
    const int lane = tid & 63;
    const int w = __builtin_amdgcn_readfirstlane(tid >> 6);   // 0..3
    const int n = blockIdx.x * 64 + lane;    // N = 131072 = 2048*64 exact

    float xd0 = xd_p[n * 3 + 0], xd1 = xd_p[n * 3 + 1], xd2 = xd_p[n * 3 + 2];
    float x0 = x_init[n * 3 + 0], x1 = x_init[n * 3 + 1], x2 = x_init[n * 3 + 2];
    float J0 = Jinv_init[n * 9 + 0], J1 = Jinv_init[n * 9 + 1], J2 = Jinv_init[n * 9 + 2];
    float J3 = Jinv_init[n * 9 + 3], J4 = Jinv_init[n * 9 + 4], J5 = Jinv_init[n * 9 + 5];
    float J6 = Jinv_init[n * 9 + 6], J7 = Jinv_init[n * 9 + 7], J8 = Jinv_init[n * 9 + 8];

    float g0, g1, g2;
    eval_g_quad(part, w, lane, W0, b0, W1, b1, W2, b2, tfs,
                x0, x1, x2, xd0, xd1, xd2, g0, g1, g2);

    float u0 = -(fmaf(J0, g0, fmaf(J1, g1, J2 * g2)));
    float u1 = -(fmaf(J3, g0, fmaf(J4, g1, J5 * g2)));
    float u2 = -(fmaf(J6, g0, fmaf(J7, g1, J8 * g2)));

    float gn_opt = sqrtf(g0 * g0 + g1 * g1 + g2 * g2);
    float xo0 = x0, xo1 = x1, xo2 = x2;
    bool ids = true;   // reference initializes ids = ones(bool)

    for (int step = 0; step < MAX_STEPS; ++step) {
        // identical ids in all 4 waves -> identical ballot -> uniform break
        if (__ballot(ids) == 0ull) break;

        float dx0 = ids ? u0 : 0.f, dx1 = ids ? u1 : 0.f, dx2 = ids ? u2 : 0.f;
        x0 += dx0; x1 += dx1; x2 += dx2;

        float ng0, ng1, ng2;
        eval_g_quad(part, w, lane, W0, b0, W1, b1, W2, b2, tfs,
                    x0, x1, x2, xd0, xd1, xd2, ng0, ng1, ng2);
        float dg0 = ng0 - g0, dg1 = ng1 - g1, dg2 = ng2 - g2;
        g0 = ng0; g1 = ng1; g2 = ng2;

        float gn = sqrtf(g0 * g0 + g1 * g1 + g2 * g2);
        bool better = gn < gn_opt;              // false for NaN (matches jnp.where)
        if (better) { gn_opt = gn; xo0 = x0; xo1 = x1; xo2 = x2; }
        bool ids_new = (gn_opt > CVG_T) && (gn < DVG_T);

        float vT0 = fmaf(dx0, J0, fmaf(dx1, J3, dx2 * J6));
        float vT1 = fmaf(dx0, J1, fmaf(dx1, J4, dx2 * J7));
        float vT2 = fmaf(dx0, J2, fmaf(dx1, J5, dx2 * J8));
        float a0 = dx0 - fmaf(J0, dg0, fmaf(J1, dg1, J2 * dg2));
        float a1 = dx1 - fmaf(J3, dg0, fmaf(J4, dg1, J5 * dg2));
        float a2 = dx2 - fmaf(J6, dg0, fmaf(J7, dg1, J8 * dg2));
        float bb = fmaf(vT0, dg0, fmaf(vT1, dg1, vT2 * dg2));
        bb += (bb >= 0.f) ? EPS_B : -EPS_B;
        // select (NOT multiply) so NaN can't leak into J when masked off
        float iu0 = ids_new ? (a0 / bb) : 0.f;
        float iu1 = ids_new ? (a1 / bb) : 0.f;
        float iu2 = ids_new ? (a2 / bb) : 0.f;
        J0 = fmaf(iu0, vT0, J0); J1 = fmaf(iu0, vT1, J1); J2 = fmaf(iu0, vT2, J2);
        J3 = fmaf(iu1, vT0, J3); J4 = fmaf(iu1, vT1, J4); J5 = fmaf(iu1, vT2, J5);
        J6 = fmaf(iu2, vT0, J6); J7 = fmaf(iu2, vT1, J7); J8 = fmaf(iu2, vT2, J8);

        u0 = -(fmaf(J0, g0, fmaf(J1, g1, J2 * g2)));
        u1 = -(fmaf(J3, g0, fmaf(J4, g1, J5 * g2)));
        u2 = -(fmaf(J6, g0, fmaf(J7, g1, J8 * g2)));
        ids = ids_new;
    }

    // outputs: x_opt (N,3,1) | gn_opt (N) | valid (N) as 0.0/1.0
    if (w == 0) {
        out[n * 3 + 0] = xo0;
        out[n * 3 + 1] = xo1;
        out[n * 3 + 2] = xo2;
        out[3 * N + n] = gn_opt;
        out[4 * N + n] = (gn_opt < CVG_T) ? 1.0f : 0.0f;
    }
}

extern "C" void kernel_launch(void* const* d_in, const int* in_sizes, int n_in,
                              void* d_out, int out_size, void* d_ws, size_t ws_size,
                              hipStream_t stream) {
    const float* xd     = (const float*)d_in[0];
    const float* x_init = (const float*)d_in[1];
    const float* Jinv   = (const float*)d_in[2];
    const float* tfs    = (const float*)d_in[3];
    const float* W0     = (const float*)d_in[4];
    const float* b0     = (const float*)d_in[5];
    const float* W1     = (const float*)d_in[6];
    const float* b1     = (const float*)d_in[7];
    const float* W2     = (const float*)d_in[8];
    const float* b2     = (const float*)d_in[9];
    float* out = (float*)d_out;

    const int N = in_sizes[0] / 3;
    dim3 block(256);                 // 4 waves, 64 points per block
    dim3 grid((N + 63) / 64);

    hipLaunchKernelGGL(broyden_quad_kernel, grid, block, 0, stream,
                       xd, x_init, Jinv, tfs, W0, b0, W1, b1, W2, b2, out, N);
}